// Round 4
// baseline (81841.785 us; speedup 1.0000x reference)
//
#include <hip/hip_runtime.h>
#include <hip/hip_bf16.h>

#define H      1024
#define IN_DIM 512
#define OD     512
#define T_LEN  16384
#define NWG    64     // one WG per 16 hidden units; weights live in registers
#define UPW    16     // units per WG
#define UPWAVE 4      // units per wave (one per lane 0..3 at gate time)

typedef unsigned long long u64;
typedef unsigned int u32;

__device__ __forceinline__ u32 pack_bf(float lo, float hi) {
    u32 a = __float_as_uint(lo); a = (a + 0x7fffu + ((a >> 16) & 1u)) >> 16;          // RNE -> [15:0]
    u32 b = __float_as_uint(hi); b = (b + 0x7fffu + ((b >> 16) & 1u)) & 0xffff0000u;  // RNE -> [31:16]
    return a | b;
}
__device__ __forceinline__ float bf_lo(u32 pk) { return __uint_as_float(pk << 16); }
__device__ __forceinline__ float bf_hi(u32 pk) { return __uint_as_float(pk & 0xffff0000u); }

// LDS float4-slot XOR swizzle: logical float4 j -> slot j ^ ((j>>3)&7).
// Spreads the lane*16-stride gather (else 32-way bank conflict) to ~2-way.
__device__ __forceinline__ int swz(int j) { return j ^ ((j >> 3) & 7); }

// 64 persistent WGs, direct tag-polling, no sequencer.
// pairs[parity][u] = (tag<<32)|f32bits; tag T == h after T steps (h_0 = 0).
// Every WG ingests all 1024 pairs each step (data arrives WITH the detect).
// Race-freedom (tag monotonicity): WG publishes tag t+1 only after its full
// ingest of tag t (data deps through shuffles force every lane's reads);
// an overwrite of parity-p (tag t+2) requires observing ALL tag-t+1 pairs,
// which requires every WG's tag-t ingest to have completed.
__global__ __launch_bounds__(256, 1)
void gru_rec_kernel(const float* __restrict__ X,
                    const float* __restrict__ Wih,
                    const float* __restrict__ Whh,
                    const float* __restrict__ bih,
                    const float* __restrict__ bhh,
                    float* __restrict__ hs,
                    u64* __restrict__ pairs)   // [2][H]
{
    __shared__ float hsh[H];   // swizzled at float4 granularity

    const int tid  = threadIdx.x;
    const int wave = tid >> 6;
    const int lane = tid & 63;
    const int wg   = blockIdx.x;
    const int q0   = wg * UPW + wave * UPWAVE;   // first unit of this wave

    // ---- weights -> registers (bf16 pairs). rows 0..3 r, 4..7 z, 8..11 n ----
    u32 whh[12][8];   // h-slice: 16 bf16 (cols lane*16 .. +15)
    u32 wih[12][4];   // x-slice:  8 bf16 (cols lane*8  .. +7)
    #pragma unroll
    for (int row = 0; row < 12; ++row) {
        const int g = row >> 2, j = row & 3;
        const float* wr = Whh + (size_t)(g * H + q0 + j) * H + lane * 16;
        #pragma unroll
        for (int k = 0; k < 8; ++k) whh[row][k] = pack_bf(wr[2*k], wr[2*k+1]);
        const float* wx = Wih + (size_t)(g * H + q0 + j) * IN_DIM + lane * 8;
        #pragma unroll
        for (int k = 0; k < 4; ++k) wih[row][k] = pack_bf(wx[2*k], wx[2*k+1]);
    }
    float bxr = 0.f, bxz = 0.f, bxn = 0.f, bhr = 0.f, bhz = 0.f, bhn = 0.f;
    if (lane < UPWAVE) {
        const int u = q0 + lane;
        bxr = bih[u]; bxz = bih[H + u]; bxn = bih[2 * H + u];
        bhr = bhh[u]; bhz = bhh[H + u]; bhn = bhh[2 * H + u];
    }

    // ---- x row prefetch (t=0) ----
    float xv[8], xw[8];
    {
        const float4* xp = (const float4*)X;
        float4 a = xp[lane * 2], b = xp[lane * 2 + 1];
        xv[0]=a.x; xv[1]=a.y; xv[2]=a.z; xv[3]=a.w;
        xv[4]=b.x; xv[5]=b.y; xv[6]=b.z; xv[7]=b.w;
    }

    const int rdu = (tid + wg * 4) & 255;        // staggered: my float4-group of pairs

    #pragma unroll 1
    for (int t = 0; t < T_LEN; ++t) {
        // prefetch next x row (in flight during the spin)
        {
            const int tn = (t + 1 < T_LEN) ? (t + 1) : t;
            const float4* xp = (const float4*)(X + (size_t)tn * IN_DIM);
            float4 a = xp[lane * 2], b = xp[lane * 2 + 1];
            xw[0]=a.x; xw[1]=a.y; xw[2]=a.z; xw[3]=a.w;
            xw[4]=b.x; xw[5]=b.y; xw[6]=b.z; xw[7]=b.w;
        }

        // ---- spin on my 4 pairs: detect == data (one LLC hop) ----
        u64* pp = pairs + (size_t)(t & 1) * H + rdu * 4;
        const u32 want = (u32)t;
        u64 p0, p1, p2, p3;
        for (;;) {
            p0 = __hip_atomic_load(pp + 0, __ATOMIC_RELAXED, __HIP_MEMORY_SCOPE_AGENT);
            p1 = __hip_atomic_load(pp + 1, __ATOMIC_RELAXED, __HIP_MEMORY_SCOPE_AGENT);
            p2 = __hip_atomic_load(pp + 2, __ATOMIC_RELAXED, __HIP_MEMORY_SCOPE_AGENT);
            p3 = __hip_atomic_load(pp + 3, __ATOMIC_RELAXED, __HIP_MEMORY_SCOPE_AGENT);
            if ((u32)(p0 >> 32) == want && (u32)(p1 >> 32) == want &&
                (u32)(p2 >> 32) == want && (u32)(p3 >> 32) == want) break;
        }
        {
            float4 hv4 = make_float4(__uint_as_float((u32)p0), __uint_as_float((u32)p1),
                                     __uint_as_float((u32)p2), __uint_as_float((u32)p3));
            *(float4*)&hsh[swz(rdu) * 4] = hv4;
        }
        __syncthreads();   // hsh complete

        // coalesced store of PREVIOUS hs row (hsh holds tag t == reference hs[t-1])
        if (t && wg == (t & (NWG - 1))) {
            float4 hv4 = *(const float4*)&hsh[swz(tid) * 4];
            *(float4*)(hs + (size_t)(t - 1) * H + tid * 4) = hv4;
        }

        // gather my 16 h values (swizzled slots -> ~2-way banks)
        float hv[16];
        #pragma unroll
        for (int i = 0; i < 4; ++i) {
            float4 h4 = *(const float4*)&hsh[swz(lane * 4 + i) * 4];
            hv[i*4+0]=h4.x; hv[i*4+1]=h4.y; hv[i*4+2]=h4.z; hv[i*4+3]=h4.w;
        }

        // ---- 16 partial dots from registers ----
        // acc 0..3 = r (h+x), 4..7 = z (h+x), 8..11 = n_h, 12..15 = n_x
        float acc[16];
        #pragma unroll
        for (int r2 = 0; r2 < 16; ++r2) acc[r2] = 0.f;
        #pragma unroll
        for (int k = 0; k < 8; ++k) {
            const float h0 = hv[2*k], h1 = hv[2*k+1];
            #pragma unroll
            for (int row = 0; row < 12; ++row) {
                const u32 pk = whh[row][k];
                acc[row] += bf_lo(pk) * h0 + bf_hi(pk) * h1;
            }
        }
        #pragma unroll
        for (int k = 0; k < 4; ++k) {
            const float x0 = xv[2*k], x1 = xv[2*k+1];
            #pragma unroll
            for (int row = 0; row < 12; ++row) {
                const int a = (row < 8) ? row : row + 4;
                const u32 pk = wih[row][k];
                acc[a] += bf_lo(pk) * x0 + bf_hi(pk) * x1;
            }
        }

        // all-reduce the 16 sums across the wave
        #pragma unroll
        for (int s = 32; s; s >>= 1) {
            #pragma unroll
            for (int r2 = 0; r2 < 16; ++r2)
                acc[r2] += __shfl_xor(acc[r2], s, 64);
        }

        // gates + publish (lanes 0..3: unit q0+lane)
        if (lane < UPWAVE) {
            const int u = q0 + lane;
            const float hprev = hsh[swz(u >> 2) * 4 + (u & 3)];
            const float r = 1.f / (1.f + __expf(-(acc[lane]     + bxr + bhr)));
            const float z = 1.f / (1.f + __expf(-(acc[4 + lane] + bxz + bhz)));
            const float e2 = __expf(2.f * (acc[12 + lane] + bxn + r * (acc[8 + lane] + bhn)));
            const float n = 1.f - 2.f / (e2 + 1.f);   // tanh
            const float hnew = (1.f - z) * n + z * hprev;
            const u64 pk = ((u64)(u32)(t + 1) << 32) | (u64)__float_as_uint(hnew);
            __hip_atomic_store(pairs + (size_t)((t + 1) & 1) * H + u, pk,
                               __ATOMIC_RELAXED, __HIP_MEMORY_SCOPE_AGENT);
            if (t == T_LEN - 1)
                hs[(size_t)t * H + u] = hnew;   // final row: tag T_LEN never re-read
        }
        // no trailing __syncthreads: next-iter hsh writes are gated by tag t+1,
        // which transitively requires every lane's iter-t hsh reads (shuffle deps).

        #pragma unroll
        for (int i = 0; i < 8; ++i) xv[i] = xw[i];
    }
}

// out[m,n] = sum_k hs[m,k] * Wfc[n,k] + bfc[n]   (M=16384, N=512, K=1024)
#define BM 64
#define BN 64
#define BK 16
__global__ __launch_bounds__(256)
void fc_kernel(const float* __restrict__ A, const float* __restrict__ B,
               const float* __restrict__ bias, float* __restrict__ C)
{
    __shared__ float As[BK][BM + 4];
    __shared__ float Bs[BK][BN + 4];
    const int tid = threadIdx.x;
    const int m0 = blockIdx.y * BM, n0 = blockIdx.x * BN;
    const int tx = tid & 15, ty = tid >> 4;
    float acc[4][4] = {};
    const int r = tid >> 2, c = (tid & 3) << 2;
    for (int k0 = 0; k0 < H; k0 += BK) {
        float4 va = *(const float4*)(A + (size_t)(m0 + r) * H + (k0 + c));
        As[c + 0][r] = va.x; As[c + 1][r] = va.y; As[c + 2][r] = va.z; As[c + 3][r] = va.w;
        float4 vb = *(const float4*)(B + (size_t)(n0 + r) * H + (k0 + c));
        Bs[c + 0][r] = vb.x; Bs[c + 1][r] = vb.y; Bs[c + 2][r] = vb.z; Bs[c + 3][r] = vb.w;
        __syncthreads();
        #pragma unroll
        for (int kk = 0; kk < BK; ++kk) {
            float4 a4 = *(const float4*)&As[kk][ty * 4];
            float4 b4 = *(const float4*)&Bs[kk][tx * 4];
            const float av[4] = {a4.x, a4.y, a4.z, a4.w};
            const float bv[4] = {b4.x, b4.y, b4.z, b4.w};
            #pragma unroll
            for (int i = 0; i < 4; ++i)
                #pragma unroll
                for (int j = 0; j < 4; ++j)
                    acc[i][j] += av[i] * bv[j];
        }
        __syncthreads();
    }
    #pragma unroll
    for (int i = 0; i < 4; ++i) {
        const int m = m0 + ty * 4 + i;
        #pragma unroll
        for (int j = 0; j < 4; ++j) {
            const int n = n0 + tx * 4 + j;
            C[(size_t)m * OD + n] = acc[i][j] + bias[n];
        }
    }
}

extern "C" void kernel_launch(void* const* d_in, const int* in_sizes, int n_in,
                              void* d_out, int out_size, void* d_ws, size_t ws_size,
                              hipStream_t stream) {
    const float* X   = (const float*)d_in[0];
    const float* Wih = (const float*)d_in[1];
    const float* Whh = (const float*)d_in[2];
    const float* bih = (const float*)d_in[3];
    const float* bhh = (const float*)d_in[4];
    const float* Wfc = (const float*)d_in[5];
    const float* bfc = (const float*)d_in[6];
    float* out = (float*)d_out;

    float* hs    = (float*)d_ws;                                  // 64 MB
    u64*   pairs = (u64*)((char*)d_ws + (size_t)T_LEN * H * 4);   // 16 KB

    // tag 0 / value 0.0 == initial hidden state on both parities
    hipMemsetAsync(pairs, 0, 2 * H * sizeof(u64), stream);

    void* args[] = { (void*)&X, (void*)&Wih, (void*)&Whh, (void*)&bih,
                     (void*)&bhh, (void*)&hs, (void*)&pairs };
    hipError_t e = hipLaunchCooperativeKernel((const void*)gru_rec_kernel,
                                              dim3(NWG), dim3(256), args, 0, stream);
    if (e != hipSuccess) {
        gru_rec_kernel<<<dim3(NWG), dim3(256), 0, stream>>>(X, Wih, Whh, bih, bhh, hs, pairs);
    }

    dim3 fgrid(OD / BN, T_LEN / BM);
    fc_kernel<<<fgrid, dim3(256), 0, stream>>>(hs, Wfc, bfc, out);
}

// Round 5
// 31375.479 us; speedup vs baseline: 2.6085x; 2.6085x over previous
//
#include <hip/hip_runtime.h>
#include <hip/hip_bf16.h>

#define H      1024
#define IN_DIM 512
#define OD     512
#define T_LEN  16384
#define NWG    256   // one WG per 4 hidden units (unit per wave)
#define NREP   8     // pair-array replicas (contention spreading)

typedef unsigned long long u64;
typedef unsigned int u32;

__device__ __forceinline__ u32 pack_bf(float lo, float hi) {
    u32 a = __float_as_uint(lo); a = (a + 0x7fffu + ((a >> 16) & 1u)) >> 16;          // RNE -> [15:0]
    u32 b = __float_as_uint(hi); b = (b + 0x7fffu + ((b >> 16) & 1u)) & 0xffff0000u;  // RNE -> [31:16]
    return a | b;
}
__device__ __forceinline__ float bf_lo(u32 pk) { return __uint_as_float(pk << 16); }
__device__ __forceinline__ float bf_hi(u32 pk) { return __uint_as_float(pk & 0xffff0000u); }

// 256 persistent WGs, unit-per-wave, direct tag-polling on REPLICATED pairs.
// preplicas[r][parity][u] = (tag<<32)|f32bits; tag T == h after T steps (h_0=0).
// Producers (lane 0 of each wave) write their unit to ALL 8 replicas; consumer
// WG polls ONLY replica wg&7 -> 8x fewer readers per LLC line, still one hop
// (the polled word IS the data). Race-freedom (tag monotonicity, per replica):
// any WG's publish of tag t+1 happens after its whole WG passed the leading
// __syncthreads for step t (i.e. fully ingested tag-t from its replica);
// overwrite of tag-t slots (tag t+2, end of iter t+1) requires the writer to
// have seen ALL tags t+1, hence every WG ingested tag t. Trailing
// __syncthreads protects intra-WG hsh WAR.
__global__ __launch_bounds__(256, 1)
void gru_rec_kernel(const float* __restrict__ X,
                    const float* __restrict__ Wih,
                    const float* __restrict__ Whh,
                    const float* __restrict__ bih,
                    const float* __restrict__ bhh,
                    float* __restrict__ hs,
                    u64* __restrict__ pairs)   // [NREP][2][H]
{
    __shared__ float hsh[H];

    const int tid  = threadIdx.x;
    const int wave = tid >> 6;
    const int lane = tid & 63;
    const int wg   = blockIdx.x;
    const int u    = wg * 4 + wave;            // this wave's hidden unit

    // ---- weights -> registers, bf16-packed; lane l owns cols {2l,2l+1}+128c ----
    u32 whh_r[3][8];   // gates r,z,n over H   (c = 0..7)
    u32 wih_r[3][4];   // gates r,z,n over IN  (c = 0..3)
    #pragma unroll
    for (int g = 0; g < 3; ++g) {
        const float* wr = Whh + (size_t)(g * H + u) * H;
        #pragma unroll
        for (int c = 0; c < 8; ++c)
            whh_r[g][c] = pack_bf(wr[2 * lane + 128 * c], wr[2 * lane + 1 + 128 * c]);
        const float* wx = Wih + (size_t)(g * H + u) * IN_DIM;
        #pragma unroll
        for (int c = 0; c < 4; ++c)
            wih_r[g][c] = pack_bf(wx[2 * lane + 128 * c], wx[2 * lane + 1 + 128 * c]);
    }
    const float bxr = bih[u], bxz = bih[H + u], bxn = bih[2 * H + u];
    const float bhr = bhh[u], bhz = bhh[H + u], bhn = bhh[2 * H + u];

    // ---- x row for t=0 (cols {2l,2l+1}+128c) ----
    float xv[8], xw[8];
    #pragma unroll
    for (int c = 0; c < 4; ++c) {
        float2 v = *(const float2*)(X + 2 * lane + 128 * c);
        xv[2 * c] = v.x; xv[2 * c + 1] = v.y;
    }

    const int rdu = (tid + wg * 4) & 255;          // staggered float4-group of pairs
    u64* const prep = pairs + (size_t)(wg & (NREP - 1)) * 2 * H;

    #pragma unroll 1
    for (int t = 0; t < T_LEN; ++t) {
        // ---- x partials (independent of h: off the critical path) ----
        float xr = 0.f, xz = 0.f, xn = 0.f;
        #pragma unroll
        for (int c = 0; c < 4; ++c) {
            const float x0 = xv[2 * c], x1 = xv[2 * c + 1];
            xr += bf_lo(wih_r[0][c]) * x0 + bf_hi(wih_r[0][c]) * x1;
            xz += bf_lo(wih_r[1][c]) * x0 + bf_hi(wih_r[1][c]) * x1;
            xn += bf_lo(wih_r[2][c]) * x0 + bf_hi(wih_r[2][c]) * x1;
        }
        // reduce xn now (needed separately: n = tanh(gxn + r*ghn))
        float xns = xn;
        #pragma unroll
        for (int s = 32; s; s >>= 1) xns += __shfl_xor(xns, s, 64);

        // prefetch next x row (in flight during the spin)
        {
            const int tn = (t + 1 < T_LEN) ? (t + 1) : t;
            const float* xp = X + (size_t)tn * IN_DIM;
            #pragma unroll
            for (int c = 0; c < 4; ++c) {
                float2 v = *(const float2*)(xp + 2 * lane + 128 * c);
                xw[2 * c] = v.x; xw[2 * c + 1] = v.y;
            }
        }

        // ---- spin on my replica's 4 pairs: detect == data (one LLC hop) ----
        u64* pp = prep + (size_t)(t & 1) * H + rdu * 4;
        const u32 want = (u32)t;
        u64 p0, p1, p2, p3;
        for (;;) {
            p0 = __hip_atomic_load(pp + 0, __ATOMIC_RELAXED, __HIP_MEMORY_SCOPE_AGENT);
            p1 = __hip_atomic_load(pp + 1, __ATOMIC_RELAXED, __HIP_MEMORY_SCOPE_AGENT);
            p2 = __hip_atomic_load(pp + 2, __ATOMIC_RELAXED, __HIP_MEMORY_SCOPE_AGENT);
            p3 = __hip_atomic_load(pp + 3, __ATOMIC_RELAXED, __HIP_MEMORY_SCOPE_AGENT);
            if ((u32)(p0 >> 32) == want && (u32)(p1 >> 32) == want &&
                (u32)(p2 >> 32) == want && (u32)(p3 >> 32) == want) break;
        }
        {
            float4 hv4 = make_float4(__uint_as_float((u32)p0), __uint_as_float((u32)p1),
                                     __uint_as_float((u32)p2), __uint_as_float((u32)p3));
            *(float4*)&hsh[rdu * 4] = hv4;
        }
        __syncthreads();   // hsh complete

        // coalesced store of PREVIOUS hs row (hsh holds tag t == reference hs[t-1])
        if (t && wg == (t & (NWG - 1))) {
            float4 hv4 = *(const float4*)&hsh[tid * 4];
            *(float4*)(hs + (size_t)(t - 1) * H + tid * 4) = hv4;
        }

        // ---- h partials: conflict-free float2 gathers (bank 2l, 2 lanes/bank) ----
        float ar = xr, az = xz, anh = 0.f;
        #pragma unroll
        for (int c = 0; c < 8; ++c) {
            float2 h2 = *(const float2*)&hsh[2 * lane + 128 * c];
            ar  += bf_lo(whh_r[0][c]) * h2.x + bf_hi(whh_r[0][c]) * h2.y;
            az  += bf_lo(whh_r[1][c]) * h2.x + bf_hi(whh_r[1][c]) * h2.y;
            anh += bf_lo(whh_r[2][c]) * h2.x + bf_hi(whh_r[2][c]) * h2.y;
        }

        // butterfly all-reduce of 3 sums
        #pragma unroll
        for (int s = 32; s; s >>= 1) {
            ar  += __shfl_xor(ar,  s, 64);
            az  += __shfl_xor(az,  s, 64);
            anh += __shfl_xor(anh, s, 64);
        }

        // ---- gates + replicated publish (lane 0) ----
        if (lane == 0) {
            const float hprev = hsh[u];
            const float r = 1.f / (1.f + __expf(-(ar + bxr + bhr)));
            const float z = 1.f / (1.f + __expf(-(az + bxz + bhz)));
            const float e2 = __expf(2.f * (xns + bxn + r * (anh + bhn)));
            const float n = 1.f - 2.f / (e2 + 1.f);   // tanh
            const float hnew = (1.f - z) * n + z * hprev;
            const u64 pk = ((u64)(u32)(t + 1) << 32) | (u64)__float_as_uint(hnew);
            const size_t slot = (size_t)((t + 1) & 1) * H + u;
            #pragma unroll
            for (int rp = 0; rp < NREP; ++rp)
                __hip_atomic_store(pairs + (size_t)rp * 2 * H + slot, pk,
                                   __ATOMIC_RELAXED, __HIP_MEMORY_SCOPE_AGENT);
            if (t == T_LEN - 1)
                hs[(size_t)t * H + u] = hnew;   // final row: tag T_LEN never re-read
        }
        __syncthreads();   // WAR: hsh reads of step t vs writes of step t+1

        #pragma unroll
        for (int i = 0; i < 8; ++i) xv[i] = xw[i];
    }
}

// out[m,n] = sum_k hs[m,k] * Wfc[n,k] + bfc[n]   (M=16384, N=512, K=1024)
#define BM 64
#define BN 64
#define BK 16
__global__ __launch_bounds__(256)
void fc_kernel(const float* __restrict__ A, const float* __restrict__ B,
               const float* __restrict__ bias, float* __restrict__ C)
{
    __shared__ float As[BK][BM + 4];
    __shared__ float Bs[BK][BN + 4];
    const int tid = threadIdx.x;
    const int m0 = blockIdx.y * BM, n0 = blockIdx.x * BN;
    const int tx = tid & 15, ty = tid >> 4;
    float acc[4][4] = {};
    const int r = tid >> 2, c = (tid & 3) << 2;
    for (int k0 = 0; k0 < H; k0 += BK) {
        float4 va = *(const float4*)(A + (size_t)(m0 + r) * H + (k0 + c));
        As[c + 0][r] = va.x; As[c + 1][r] = va.y; As[c + 2][r] = va.z; As[c + 3][r] = va.w;
        float4 vb = *(const float4*)(B + (size_t)(n0 + r) * H + (k0 + c));
        Bs[c + 0][r] = vb.x; Bs[c + 1][r] = vb.y; Bs[c + 2][r] = vb.z; Bs[c + 3][r] = vb.w;
        __syncthreads();
        #pragma unroll
        for (int kk = 0; kk < BK; ++kk) {
            float4 a4 = *(const float4*)&As[kk][ty * 4];
            float4 b4 = *(const float4*)&Bs[kk][tx * 4];
            const float av[4] = {a4.x, a4.y, a4.z, a4.w};
            const float bv[4] = {b4.x, b4.y, b4.z, b4.w};
            #pragma unroll
            for (int i = 0; i < 4; ++i)
                #pragma unroll
                for (int j = 0; j < 4; ++j)
                    acc[i][j] += av[i] * bv[j];
        }
        __syncthreads();
    }
    #pragma unroll
    for (int i = 0; i < 4; ++i) {
        const int m = m0 + ty * 4 + i;
        #pragma unroll
        for (int j = 0; j < 4; ++j) {
            const int n = n0 + tx * 4 + j;
            C[(size_t)m * OD + n] = acc[i][j] + bias[n];
        }
    }
}

extern "C" void kernel_launch(void* const* d_in, const int* in_sizes, int n_in,
                              void* d_out, int out_size, void* d_ws, size_t ws_size,
                              hipStream_t stream) {
    const float* X   = (const float*)d_in[0];
    const float* Wih = (const float*)d_in[1];
    const float* Whh = (const float*)d_in[2];
    const float* bih = (const float*)d_in[3];
    const float* bhh = (const float*)d_in[4];
    const float* Wfc = (const float*)d_in[5];
    const float* bfc = (const float*)d_in[6];
    float* out = (float*)d_out;

    float* hs    = (float*)d_ws;                                  // 64 MB
    u64*   pairs = (u64*)((char*)d_ws + (size_t)T_LEN * H * 4);   // NREP*2*H*8 = 128 KB

    // all replicas: tag 0 / value 0.0 == initial hidden state
    hipMemsetAsync(pairs, 0, (size_t)NREP * 2 * H * sizeof(u64), stream);

    void* args[] = { (void*)&X, (void*)&Wih, (void*)&Whh, (void*)&bih,
                     (void*)&bhh, (void*)&hs, (void*)&pairs };
    hipError_t e = hipLaunchCooperativeKernel((const void*)gru_rec_kernel,
                                              dim3(NWG), dim3(256), args, 0, stream);
    if (e != hipSuccess) {
        gru_rec_kernel<<<dim3(NWG), dim3(256), 0, stream>>>(X, Wih, Whh, bih, bhh, hs, pairs);
    }

    dim3 fgrid(OD / BN, T_LEN / BM);
    fc_kernel<<<fgrid, dim3(256), 0, stream>>>(hs, Wfc, bfc, out);
}